// Round 12
// baseline (476.134 us; speedup 1.0000x reference)
//
#include <hip/hip_runtime.h>
#include <hip/hip_bf16.h>

using bf16 = __bf16;
typedef __bf16 bf16x4 __attribute__((ext_vector_type(4)));
typedef __bf16 bf16x8 __attribute__((ext_vector_type(8)));
typedef float f32x4 __attribute__((ext_vector_type(4)));
typedef float f32x16 __attribute__((ext_vector_type(16)));
typedef unsigned uint2v __attribute__((ext_vector_type(2)));

static constexpr int BATCH = 4;
static constexpr int SEQ   = 2048;
static constexpr int DIN   = 512;
static constexpr int NHEAD = 8;
static constexpr int DMID  = 2048;
static constexpr int MROWS = BATCH * SEQ;   // 8192

// softmax scale folded into Q (fp32, QKV epilogue): 1/sqrt(64) * log2(e)
static constexpr float QSCL = 0.125f * 1.4426950408889634f;

// ---------------------------------------------------------------------------
// global -> LDS direct DMA, 16 B per lane (global_load_lds_dwordx4).
// ---------------------------------------------------------------------------
__device__ __forceinline__ void gload16(const void* g, void* l)
{
    __builtin_amdgcn_global_load_lds(
        (const __attribute__((address_space(1))) unsigned int*)g,
        (__attribute__((address_space(3))) unsigned int*)l, 16, 0, 0);
}

// v_cvt_pk_bf16_f32: low16 = bf16(a), high16 = bf16(b)  (no builtin on gfx950)
__device__ __forceinline__ unsigned cvtpk(float a, float b)
{
    unsigned r;
    asm("v_cvt_pk_bf16_f32 %0, %1, %2" : "=v"(r) : "v"(a), "v"(b));
    return r;
}

// raw v_exp_f32 (libm exp2f expands to ~6 instr of denorm handling)
__device__ __forceinline__ float fexp2(float x)
{
    float r;
    asm("v_exp_f32 %0, %1" : "=v"(r) : "v"(x));
    return r;
}

// LDS-only barrier: drains lgkmcnt but NOT vmcnt, so in-flight global->reg
// prefetch loads survive the barrier (hipcc's __syncthreads drains vmcnt(0),
// exposing the full load latency every tile -- verified: attn r7->r10 -5.6us).
__device__ __forceinline__ void barrier_lds()
{
    asm volatile("s_waitcnt lgkmcnt(0)" ::: "memory");
    __builtin_amdgcn_s_barrier();
    __builtin_amdgcn_sched_barrier(0);
}

// ---------------------------------------------------------------------------
// FUSED: six weight transposes (0..3071) + mask check (3072..4095) +
// q/k/v fp32->bf16 cast (4096..7167).  Unchanged (verified).
// ---------------------------------------------------------------------------
__global__ __launch_bounds__(256) void tw_mask(
    const float* __restrict__ WQ, const float* __restrict__ WK,
    const float* __restrict__ WV, const float* __restrict__ WO,
    const float* __restrict__ W1, const float* __restrict__ W2,
    bf16* __restrict__ WQt, bf16* __restrict__ WKt, bf16* __restrict__ WVt,
    bf16* __restrict__ WOt, bf16* __restrict__ W1t, bf16* __restrict__ W2t,
    const float* __restrict__ q, const float* __restrict__ k,
    const float* __restrict__ v,
    bf16* __restrict__ qb, bf16* __restrict__ kb, bf16* __restrict__ vb,
    const uint4* __restrict__ mask, int* __restrict__ flag)
{
    const int bid = blockIdx.x;
    if (bid >= 4096) {
        const int idx = bid - 4096;
        const float* src = idx < 1024 ? q : idx < 2048 ? k : v;
        bf16*       dst = idx < 1024 ? qb : idx < 2048 ? kb : vb;
        const size_t b4 = (size_t)(idx & 1023) * 1024;
#pragma unroll
        for (int i = 0; i < 4; ++i) {
            const float4 f = reinterpret_cast<const float4*>(src)[b4 + i * 256 + threadIdx.x];
            bf16x4 h;
            h[0] = (bf16)f.x; h[1] = (bf16)f.y; h[2] = (bf16)f.z; h[3] = (bf16)f.w;
            reinterpret_cast<bf16x4*>(dst)[b4 + i * 256 + threadIdx.x] = h;
        }
        return;
    }
    if (bid >= 3072) {
        const uint4* p = mask + (size_t)(bid - 3072) * 4096;
        unsigned nz = 0;
#pragma unroll
        for (int i = 0; i < 16; ++i) {
            const uint4 u = p[i * 256 + threadIdx.x];
            nz |= u.x | u.y | u.z | u.w;
        }
        if (nz) atomicOr(flag, 1);
        return;
    }
    __shared__ float tile[32][33];
    const float* in; bf16* out; int ip, op, cx, ry;
    if (bid < 1024) {
        const int w = bid >> 8, idx = bid & 255;
        in  = w == 0 ? WQ  : w == 1 ? WK  : w == 2 ? WV  : WO;
        out = w == 0 ? WQt : w == 1 ? WKt : w == 2 ? WVt : WOt;
        ip = 512; op = 512; cx = idx & 15; ry = idx >> 4;
    } else if (bid < 2048) {
        const int idx = bid - 1024;
        in = W1; out = W1t; ip = 2048; op = 512; cx = idx & 63; ry = idx >> 6;
    } else {
        const int idx = bid - 2048;
        in = W2; out = W2t; ip = 512; op = 2048; cx = idx & 15; ry = idx >> 4;
    }
    const int c0 = cx * 32, r0 = ry * 32;
    const int tx = threadIdx.x & 31, ty = threadIdx.x >> 5;
    for (int i = 0; i < 32; i += 8)
        tile[ty + i][tx] = in[(size_t)(r0 + ty + i) * ip + c0 + tx];
    __syncthreads();
    for (int i = 0; i < 32; i += 8)
        out[(size_t)(c0 + ty + i) * op + r0 + tx] = (bf16)tile[tx][ty + i];
}

// ---------------------------------------------------------------------------
// 128x128-tile GEMM (m97 structure) for W1 (N=2048). Unchanged (verified).
// ---------------------------------------------------------------------------
template <int ACT>
__global__ __launch_bounds__(256) void gemm128(const bf16* __restrict__ A,
                                               const bf16* __restrict__ Bt,
                                               bf16* __restrict__ C,
                                               int N, int K)
{
    __shared__ bf16 sA[128 * 64];
    __shared__ bf16 sB[128 * 64];

    const int t    = threadIdx.x;
    const int lane = t & 63;
    const int wave = t >> 6;
    const int wm   = wave >> 1;
    const int wn   = wave & 1;
    const int lr   = lane & 15;
    const int lq   = lane >> 4;

    const int m0 = blockIdx.y * 128;
    const int n0 = blockIdx.x * 128;

    const int srow = lane >> 3;
    const int scol = (lane & 7) * 8;

    f32x4 acc[4][4] = {};

    for (int k0 = 0; k0 < K; k0 += 64) {
        if (k0) __syncthreads();
#pragma unroll
        for (int i = 0; i < 4; ++i) {
            const int ch = wave * 4 + i;
            const int r  = ch * 8 + srow;
            gload16(A  + (size_t)(m0 + r) * K + k0 + scol, sA + ch * 512);
            gload16(Bt + (size_t)(n0 + r) * K + k0 + scol, sB + ch * 512);
        }
        __syncthreads();

#pragma unroll
        for (int kk = 0; kk < 2; ++kk) {
            bf16x8 af[4], bfr[4];
#pragma unroll
            for (int x = 0; x < 4; ++x) {
                af[x]  = *reinterpret_cast<const bf16x8*>(&sA[(wm * 64 + x * 16 + lr) * 64 + kk * 32 + lq * 8]);
                bfr[x] = *reinterpret_cast<const bf16x8*>(&sB[(wn * 64 + x * 16 + lr) * 64 + kk * 32 + lq * 8]);
            }
#pragma unroll
            for (int m = 0; m < 4; ++m)
#pragma unroll
                for (int n = 0; n < 4; ++n)
                    acc[m][n] = __builtin_amdgcn_mfma_f32_16x16x32_bf16(af[m], bfr[n], acc[m][n], 0, 0, 0);
        }
    }

#pragma unroll
    for (int n = 0; n < 4; ++n) {
        const int col = n0 + wn * 64 + n * 16 + lr;
#pragma unroll
        for (int m = 0; m < 4; ++m) {
            const int rowb = m0 + wm * 64 + m * 16 + lq * 4;
#pragma unroll
            for (int j = 0; j < 4; ++j) {
                float v = acc[m][n][j];
                if (ACT == 1) v = v > 0.f ? v : 0.f;
                C[(size_t)(rowb + j) * N + col] = (bf16)v;
            }
        }
    }
}

// ---------------------------------------------------------------------------
// QKV projection, pure-bf16 A, 64x128 tile; V written transposed to Vt.
// Q output pre-scaled by QSCL in fp32.  Unchanged (verified).
// ---------------------------------------------------------------------------
__global__ __launch_bounds__(256) void gemm64_qkvb(const bf16* __restrict__ qb,
                                                   const bf16* __restrict__ kb,
                                                   const bf16* __restrict__ vb,
                                                   const bf16* __restrict__ WQt,
                                                   const bf16* __restrict__ WKt,
                                                   const bf16* __restrict__ WVt,
                                                   bf16* __restrict__ Qb,
                                                   bf16* __restrict__ Kb,
                                                   bf16* __restrict__ Vt)
{
    __shared__ bf16 sA[64 * 64];
    __shared__ bf16 sB[128 * 64];

    const bf16* A  = blockIdx.z == 0 ? qb  : blockIdx.z == 1 ? kb  : vb;
    const bf16* Bt = blockIdx.z == 0 ? WQt : blockIdx.z == 1 ? WKt : WVt;
    const int K = DIN;

    const int t    = threadIdx.x;
    const int lane = t & 63;
    const int wave = t >> 6;
    const int lr   = lane & 15;
    const int lq   = lane >> 4;

    const int m0 = blockIdx.y * 64;
    const int n0 = blockIdx.x * 128;

    const int srow = lane >> 3;
    const int scol = (lane & 7) * 8;

    f32x4 acc[4][2] = {};

    for (int k0 = 0; k0 < K; k0 += 64) {
        if (k0) __syncthreads();
#pragma unroll
        for (int i = 0; i < 2; ++i) {
            const int ch = wave * 2 + i;
            gload16(A + (size_t)(m0 + ch * 8 + srow) * K + k0 + scol, sA + ch * 512);
        }
#pragma unroll
        for (int i = 0; i < 4; ++i) {
            const int ch = wave * 4 + i;
            gload16(Bt + (size_t)(n0 + ch * 8 + srow) * K + k0 + scol, sB + ch * 512);
        }
        __syncthreads();

#pragma unroll
        for (int kk = 0; kk < 2; ++kk) {
            bf16x8 af[4], bfr[2];
#pragma unroll
            for (int x = 0; x < 4; ++x)
                af[x] = *reinterpret_cast<const bf16x8*>(&sA[(x * 16 + lr) * 64 + kk * 32 + lq * 8]);
#pragma unroll
            for (int n = 0; n < 2; ++n)
                bfr[n] = *reinterpret_cast<const bf16x8*>(&sB[(wave * 32 + n * 16 + lr) * 64 + kk * 32 + lq * 8]);
#pragma unroll
            for (int m = 0; m < 4; ++m)
#pragma unroll
                for (int n = 0; n < 2; ++n)
                    acc[m][n] = __builtin_amdgcn_mfma_f32_16x16x32_bf16(af[m], bfr[n], acc[m][n], 0, 0, 0);
        }
    }

    if (blockIdx.z < 2) {
        bf16* C = blockIdx.z == 0 ? Qb : Kb;
        const float sc = blockIdx.z == 0 ? QSCL : 1.f;
#pragma unroll
        for (int n = 0; n < 2; ++n) {
            const int col = n0 + wave * 32 + n * 16 + lr;
#pragma unroll
            for (int m = 0; m < 4; ++m) {
                const int rowb = m0 + m * 16 + lq * 4;
#pragma unroll
                for (int j = 0; j < 4; ++j)
                    C[(size_t)(rowb + j) * DIN + col] = (bf16)(acc[m][n][j] * sc);
            }
        }
    } else {
        __syncthreads();
#pragma unroll
        for (int n = 0; n < 2; ++n)
#pragma unroll
            for (int m = 0; m < 4; ++m)
#pragma unroll
                for (int j = 0; j < 4; ++j)
                    sB[(wave * 32 + n * 16 + lr) * 64 + m * 16 + lq * 4 + j] = (bf16)acc[m][n][j];
        __syncthreads();
        const int c = t >> 1, half = t & 1;
#pragma unroll
        for (int qq = 0; qq < 4; ++qq) {
            const bf16x8 vv = *reinterpret_cast<const bf16x8*>(&sB[c * 64 + half * 32 + qq * 8]);
            *reinterpret_cast<bf16x8*>(Vt + (size_t)(n0 + c) * MROWS + m0 + half * 32 + qq * 8) = vv;
        }
    }
}

// ---------------------------------------------------------------------------
// Flash attention — UNCHANGED from round 11 (best measured; 2 blk/CU).
// ---------------------------------------------------------------------------
__global__ __launch_bounds__(256) void attn_kernel(const bf16* __restrict__ Qb,
                                                   const bf16* __restrict__ Kb,
                                                   const bf16* __restrict__ Vt,
                                                   const float* __restrict__ mask,
                                                   bf16* __restrict__ O,
                                                   const int* __restrict__ mzf)
{
    const int bi   = blockIdx.x;
    const int xcd  = bi & 7;
    const int slot = bi >> 3;
    const int pair = xcd * 4 + (slot >> 4);
    const int qt   = slot & 15;
    const int h    = pair >> 2;
    const int b    = pair & 3;

    const int t    = threadIdx.x;
    const int lane = t & 63;
    const int wave = t >> 6;
    const int l31  = lane & 31;
    const int hi   = lane >> 5;
    const int q0   = qt * 128;
    const bool useM = (*mzf != 0);

    __shared__ bf16 sK[64 * 64];
    __shared__ bf16 sV[64 * 64];
    __shared__ float sL[4][32];

    bf16x8 qf[4];
#pragma unroll
    for (int s = 0; s < 4; ++s)
        qf[s] = *reinterpret_cast<const bf16x8*>(
            Qb + (size_t)(b * SEQ + q0 + wave * 32 + l31) * DIN + h * 64 + s * 16 + hi * 8);

    f32x16 o0 = {}, o1 = {};
    float lacc = 0.f;

    const int sr  = t >> 2;
    const int c1  = t & 3;
    const int xsw = sr & 7;

    const bf16* kbase = Kb + (size_t)(b * SEQ) * DIN + h * 64;
    const bf16* vbase = Vt + (size_t)(h * 64 + sr) * MROWS + b * SEQ;

    constexpr float L2E = 1.4426950408889634f;

    int4 kr0 = *reinterpret_cast<const int4*>(kbase + (size_t)sr * DIN + c1 * 8);
    int4 kr1 = *reinterpret_cast<const int4*>(kbase + (size_t)sr * DIN + c1 * 8 + 32);
    int4 vr0 = *reinterpret_cast<const int4*>(vbase + c1 * 8);
    int4 vr1 = *reinterpret_cast<const int4*>(vbase + c1 * 8 + 32);

    for (int tile = 0; tile < SEQ / 64; ++tile) {
        if (tile) barrier_lds();

        *reinterpret_cast<int4*>(&sK[sr * 64 + ((c1    ) ^ xsw) * 8]) = kr0;
        *reinterpret_cast<int4*>(&sK[sr * 64 + ((c1 + 4) ^ xsw) * 8]) = kr1;
        *reinterpret_cast<int4*>(&sV[sr * 64 + ((c1    ) ^ xsw) * 8]) = vr0;
        *reinterpret_cast<int4*>(&sV[sr * 64 + ((c1 + 4) ^ xsw) * 8]) = vr1;

        if (tile + 1 < SEQ / 64) {
            const int k0 = (tile + 1) * 64;
            kr0 = *reinterpret_cast<const int4*>(kbase + (size_t)(k0 + sr) * DIN + c1 * 8);
            kr1 = *reinterpret_cast<const int4*>(kbase + (size_t)(k0 + sr) * DIN + c1 * 8 + 32);
            vr0 = *reinterpret_cast<const int4*>(vbase + k0 + c1 * 8);
            vr1 = *reinterpret_cast<const int4*>(vbase + k0 + c1 * 8 + 32);
        }
        barrier_lds();

        bf16x8 kf[2][4];
#pragma unroll
        for (int kb = 0; kb < 2; ++kb)
#pragma unroll
            for (int s = 0; s < 4; ++s) {
                const int r = kb * 32 + l31;
                kf[kb][s] = *reinterpret_cast<const bf16x8*>(
                    &sK[r * 64 + ((hi + 2 * s) ^ (r & 7)) * 8]);
            }
        bf16x8 vf[2][4];
#pragma unroll
        for (int dt = 0; dt < 2; ++dt)
#pragma unroll
            for (int c = 0; c < 4; ++c) {
                const int r = dt * 32 + l31;
                vf[dt][c] = *reinterpret_cast<const bf16x8*>(
                    &sV[r * 64 + ((hi + 2 * c) ^ (r & 7)) * 8]);
            }

        f32x16 st0 = {}, st1 = {};
#pragma unroll
        for (int s = 0; s < 4; ++s) {
            st0 = __builtin_amdgcn_mfma_f32_32x32x16_bf16(kf[0][s], qf[s], st0, 0, 0, 0);
            st1 = __builtin_amdgcn_mfma_f32_32x32x16_bf16(kf[1][s], qf[s], st1, 0, 0, 0);
        }

        float p[32];
        if (useM) {
            const float* mrow = mask + ((size_t)(b * SEQ + q0 + wave * 32 + l31)) * SEQ + tile * 64;
#pragma unroll
            for (int r = 0; r < 16; ++r) {
                const int kk = (r & 3) + 8 * (r >> 2) + 4 * hi;
                p[r]      = fexp2(st0[r] + mrow[kk]      * L2E);
                p[16 + r] = fexp2(st1[r] + mrow[32 + kk] * L2E);
            }
        } else {
#pragma unroll
            for (int r = 0; r < 16; ++r) {
                p[r]      = fexp2(st0[r]);
                p[16 + r] = fexp2(st1[r]);
            }
        }
        {
            float s0 = 0.f, s1 = 0.f, s2 = 0.f, s3 = 0.f;
#pragma unroll
            for (int r = 0; r < 8; ++r) {
                s0 += p[r];
                s1 += p[8 + r];
                s2 += p[16 + r];
                s3 += p[24 + r];
            }
            lacc += (s0 + s1) + (s2 + s3);
        }

        bf16x8 pa[4];
#pragma unroll
        for (int c = 0; c < 4; ++c) {
            const int bse = c * 8;
            unsigned u0 = cvtpk(p[bse + 0], p[bse + 1]);
            unsigned u1 = cvtpk(p[bse + 2], p[bse + 3]);
            unsigned u2 = cvtpk(p[bse + 4], p[bse + 5]);
            unsigned u3 = cvtpk(p[bse + 6], p[bse + 7]);
            const uint2v r02 = __builtin_amdgcn_permlane32_swap(u0, u2, false, false);
            const uint2v r13 = __builtin_amdgcn_permlane32_swap(u1, u3, false, false);
            union { unsigned u[4]; bf16x8 v; } pk;
            pk.u[0] = r02.x; pk.u[1] = r13.x; pk.u[2] = r02.y; pk.u[3] = r13.y;
            pa[c] = pk.v;
        }

#pragma unroll
        for (int c = 0; c < 4; ++c) {
            o0 = __builtin_amdgcn_mfma_f32_32x32x16_bf16(pa[c], vf[0][c], o0, 0, 0, 0);
            o1 = __builtin_amdgcn_mfma_f32_32x32x16_bf16(pa[c], vf[1][c], o1, 0, 0, 0);
        }
    }

    lacc += __shfl_xor(lacc, 32);
    if (hi == 0) sL[wave][l31] = lacc;

#pragma unroll
    for (int r = 0; r < 16; ++r) {
        const int qr = (r & 3) + 8 * (r >> 2) + 4 * hi;
        const float inv = 1.f / sL[wave][qr];
        const size_t rowoff = (size_t)(b * SEQ + q0 + wave * 32 + qr) * DIN + h * 64;
        O[rowoff + l31]      = (bf16)(o0[r] * inv);
        O[rowoff + 32 + l31] = (bf16)(o1[r] * inv);
    }
}

// ---------------------------------------------------------------------------
// FUSED GEMM + residual + LayerNorm (WO and W2 paths).  ROUND-12 RESTRUCTURE:
// reg-staged double-buffer with XOR-swizzled LDS + ONE lgkm-only barrier per
// K-step.  Fixes (measured r11): 16-way sB bank conflicts (9.5e6 cyc) and
// the per-step vmcnt(0) drain at __syncthreads that exposed the full stage
// latency (r8 lesson).  Per step: compute(buf b) -> ds_write tile s+1 ->
// buf b^1 (auto counted-vmcnt wait; loads had a full step to land) ->
// issue loads tile s+2 (cross barrier un-drained) -> barrier_lds.
// Hazards: reads/writes within a step touch different buffers; cross-step
// pairs sealed by the single barrier.  Reg sets unrolled x2 (rule #20).
// ---------------------------------------------------------------------------
__global__ __launch_bounds__(512) void gemm_ln(const bf16* __restrict__ A,
                                               const bf16* __restrict__ Bt,
                                               const float* __restrict__ X,
                                               bf16* __restrict__ Onb,
                                               float* __restrict__ Onf,
                                               int K)
{
    __shared__ bf16 sA[2][32 * 64];
    __shared__ bf16 sB[2][512 * 64];
    __shared__ float sRed[32][8];
    __shared__ float sMu[32];
    __shared__ float sRstd[32];

    const int t     = threadIdx.x;
    const int lane  = t & 63;
    const int w     = t >> 6;
    const int lr    = lane & 15;
    const int lq    = lane >> 4;
    const int srow  = lane >> 3;
    const int scol8 = lane & 7;         // 16B-chunk index within a 64-elem row

    const int m0 = blockIdx.x * 32;

    int4 rB0[8], rB1[8];
    int4 rA0 = {}, rA1 = {};

    auto loadRegs = [&](int s, int4* rB, int4& rA) {
        const int k0 = s * 64;
#pragma unroll
        for (int i = 0; i < 8; ++i) {
            const int row = w * 64 + i * 8 + srow;
            rB[i] = *reinterpret_cast<const int4*>(Bt + (size_t)row * K + k0 + scol8 * 8);
        }
        if (w < 4)
            rA = *reinterpret_cast<const int4*>(A + (size_t)(m0 + w * 8 + srow) * K + k0 + scol8 * 8);
    };
    auto writeLds = [&](int bb, const int4* rB, const int4& rA) {
#pragma unroll
        for (int i = 0; i < 8; ++i) {
            const int row = w * 64 + i * 8 + srow;
            *reinterpret_cast<int4*>(&sB[bb][row * 64 + ((scol8 ^ (row & 7)) * 8)]) = rB[i];
        }
        if (w < 4) {
            const int row = w * 8 + srow;
            *reinterpret_cast<int4*>(&sA[bb][row * 64 + ((scol8 ^ (row & 7)) * 8)]) = rA;
        }
    };

    f32x4 acc[2][4] = {};
    const int steps = K / 64;

    auto compute = [&](int bb) {
#pragma unroll
        for (int kk = 0; kk < 2; ++kk) {
            bf16x8 af[2], bfr[4];
#pragma unroll
            for (int m = 0; m < 2; ++m) {
                const int row = m * 16 + lr;
                af[m] = *reinterpret_cast<const bf16x8*>(
                    &sA[bb][row * 64 + (((kk * 4 + lq) ^ (row & 7)) * 8)]);
            }
#pragma unroll
            for (int n = 0; n < 4; ++n) {
                const int row = w * 64 + n * 16 + lr;
                bfr[n] = *reinterpret_cast<const bf16x8*>(
                    &sB[bb][row * 64 + (((kk * 4 + lq) ^ (row & 7)) * 8)]);
            }
#pragma unroll
            for (int m = 0; m < 2; ++m)
#pragma unroll
                for (int n = 0; n < 4; ++n)
                    acc[m][n] = __builtin_amdgcn_mfma_f32_16x16x32_bf16(af[m], bfr[n], acc[m][n], 0, 0, 0);
        }
    };

    // prologue: tile0 -> regs -> buf0; issue tile1 loads; one barrier
    loadRegs(0, rB0, rA0);
    writeLds(0, rB0, rA0);
    if (steps > 1) loadRegs(1, rB1, rA1);
    barrier_lds();

    for (int s = 0; s < steps; s += 2) {
        // even step: compute buf0; write tile s+1 (rB1) -> buf1; load s+2 -> rB0
        compute(0);
        if (s + 1 < steps) writeLds(1, rB1, rA1);
        if (s + 2 < steps) loadRegs(s + 2, rB0, rA0);
        barrier_lds();
        if (s + 1 >= steps) break;
        // odd step: compute buf1; write tile s+2 (rB0) -> buf0; load s+3 -> rB1
        compute(1);
        if (s + 2 < steps) writeLds(0, rB0, rA0);
        if (s + 3 < steps) loadRegs(s + 3, rB1, rA1);
        barrier_lds();
    }

    // residual add (fp32), in place
#pragma unroll
    for (int m = 0; m < 2; ++m)
#pragma unroll
        for (int n = 0; n < 4; ++n)
#pragma unroll
            for (int j = 0; j < 4; ++j)
                acc[m][n][j] += X[(size_t)(m0 + m * 16 + lq * 4 + j) * DIN + w * 64 + n * 16 + lr];

#pragma unroll
    for (int m = 0; m < 2; ++m)
#pragma unroll
        for (int j = 0; j < 4; ++j) {
            float s = acc[m][0][j] + acc[m][1][j] + acc[m][2][j] + acc[m][3][j];
            s += __shfl_xor(s, 1); s += __shfl_xor(s, 2);
            s += __shfl_xor(s, 4); s += __shfl_xor(s, 8);
            if (lr == 0) sRed[m * 16 + lq * 4 + j][w] = s;
        }
    __syncthreads();
    if (t < 32) {
        float s = 0.f;
#pragma unroll
        for (int ww = 0; ww < 8; ++ww) s += sRed[t][ww];
        sMu[t] = s * (1.f / DIN);
    }
    __syncthreads();

#pragma unroll
    for (int m = 0; m < 2; ++m)
#pragma unroll
        for (int j = 0; j < 4; ++j) {
            const float mu = sMu[m * 16 + lq * 4 + j];
            float s = 0.f;
#pragma unroll
            for (int n = 0; n < 4; ++n) {
                const float d = acc[m][n][j] - mu;
                s += d * d;
            }
            s += __shfl_xor(s, 1); s += __shfl_xor(s, 2);
            s += __shfl_xor(s, 4); s += __shfl_xor(s, 8);
            if (lr == 0) sRed[m * 16 + lq * 4 + j][w] = s;
        }
    __syncthreads();
    if (t < 32) {
        float s = 0.f;
#pragma unroll
        for (int ww = 0; ww < 8; ++ww) s += sRed[t][ww];
        sRstd[t] = rsqrtf(s * (1.f / DIN) + 1e-5f);
    }
    __syncthreads();

#pragma unroll
    for (int m = 0; m < 2; ++m)
#pragma unroll
        for (int j = 0; j < 4; ++j) {
            const int rl = m * 16 + lq * 4 + j;
            const float mu = sMu[rl], rstd = sRstd[rl];
            const size_t rowoff = (size_t)(m0 + rl) * DIN;
#pragma unroll
            for (int n = 0; n < 4; ++n) {
                const float r = (acc[m][n][j] - mu) * rstd;
                const int col = w * 64 + n * 16 + lr;
                if (Onb) Onb[rowoff + col] = (bf16)r;
                if (Onf) Onf[rowoff + col] = r;
            }
        }
}

// ---------------------------------------------------------------------------
extern "C" void kernel_launch(void* const* d_in, const int* in_sizes, int n_in,
                              void* d_out, int out_size, void* d_ws, size_t ws_size,
                              hipStream_t stream)
{
    const float* query = (const float*)d_in[0];
    const float* key   = (const float*)d_in[1];
    const float* value = (const float*)d_in[2];
    const float* mask  = (const float*)d_in[3];
    const float* WQ    = (const float*)d_in[4];
    const float* WK    = (const float*)d_in[5];
    const float* WV    = (const float*)d_in[6];
    const float* WO    = (const float*)d_in[7];
    const float* W1    = (const float*)d_in[8];
    const float* W2    = (const float*)d_in[9];

    char* w = (char*)d_ws;
    size_t off = 0;
    auto carve2 = [&](size_t elems) { bf16* p = (bf16*)(w + off); off += elems * 2; return p; };
    auto carve4 = [&](size_t elems) { float* p = (float*)(w + off); off += elems * 4; return p; };

    bf16* Qb    = carve2((size_t)MROWS * DIN);
    bf16* Kb    = carve2((size_t)MROWS * DIN);
    bf16* Vb    = carve2((size_t)MROWS * DIN);   // attn output (Ob)
    bf16* Vt    = carve2((size_t)MROWS * DIN);
    bf16* Mid   = carve2((size_t)MROWS * DMID);
    float* Ln1f = carve4((size_t)MROWS * DIN);
    bf16* WQt   = carve2((size_t)DIN * DIN);
    bf16* WKt   = carve2((size_t)DIN * DIN);
    bf16* WVt   = carve2((size_t)DIN * DIN);
    bf16* WOt   = carve2((size_t)DIN * DIN);
    bf16* W1t   = carve2((size_t)DIN * DMID);
    bf16* W2t   = carve2((size_t)DMID * DIN);
    int*  mzf   = (int*)(w + off); off += 16;
    if (off > ws_size) return;

    bf16* Ob   = Vb;
    bf16* Ln1b = Kb;
    bf16* qb = Mid;
    bf16* kb = Mid + (size_t)MROWS * DIN;
    bf16* vb = Mid + (size_t)2 * MROWS * DIN;

    const dim3 blk(256);

    hipMemsetAsync(mzf, 0, 4, stream);

    tw_mask<<<dim3(7168), blk, 0, stream>>>(WQ, WK, WV, WO, W1, W2,
                                            WQt, WKt, WVt, WOt, W1t, W2t,
                                            query, key, value, qb, kb, vb,
                                            (const uint4*)mask, mzf);

    gemm64_qkvb<<<dim3(DIN / 128, MROWS / 64, 3), blk, 0, stream>>>(qb, kb, vb,
                                                                    WQt, WKt, WVt, Qb, Kb, Vt);

    // attention: unchanged (2 blocks/CU)
    attn_kernel<<<dim3(512), blk, 0, stream>>>(Qb, Kb, Vt, mask, Ob, mzf);

    gemm_ln<<<dim3(MROWS / 32), dim3(512), 0, stream>>>(Ob, WOt, query, Ln1b, Ln1f, DIN);

    gemm128<1><<<dim3(DMID / 128, MROWS / 128), blk, 0, stream>>>(Ln1b, W1t, Mid, DMID, DIN);

    gemm_ln<<<dim3(MROWS / 32), dim3(512), 0, stream>>>(Mid, W2t, Ln1f,
                                                        (bf16*)nullptr, (float*)d_out, DMID);
}

// Round 13
// 327.839 us; speedup vs baseline: 1.4523x; 1.4523x over previous
//
#include <hip/hip_runtime.h>
#include <hip/hip_bf16.h>

using bf16 = __bf16;
typedef __bf16 bf16x4 __attribute__((ext_vector_type(4)));
typedef __bf16 bf16x8 __attribute__((ext_vector_type(8)));
typedef float f32x4 __attribute__((ext_vector_type(4)));
typedef float f32x16 __attribute__((ext_vector_type(16)));
typedef unsigned uint2v __attribute__((ext_vector_type(2)));

static constexpr int BATCH = 4;
static constexpr int SEQ   = 2048;
static constexpr int DIN   = 512;
static constexpr int NHEAD = 8;
static constexpr int DMID  = 2048;
static constexpr int MROWS = BATCH * SEQ;   // 8192

// softmax scale folded into Q (fp32, QKV epilogue): 1/sqrt(64) * log2(e)
static constexpr float QSCL = 0.125f * 1.4426950408889634f;

// ---------------------------------------------------------------------------
// global -> LDS direct DMA, 16 B per lane (global_load_lds_dwordx4).
// ---------------------------------------------------------------------------
__device__ __forceinline__ void gload16(const void* g, void* l)
{
    __builtin_amdgcn_global_load_lds(
        (const __attribute__((address_space(1))) unsigned int*)g,
        (__attribute__((address_space(3))) unsigned int*)l, 16, 0, 0);
}

// v_cvt_pk_bf16_f32: low16 = bf16(a), high16 = bf16(b)  (no builtin on gfx950)
__device__ __forceinline__ unsigned cvtpk(float a, float b)
{
    unsigned r;
    asm("v_cvt_pk_bf16_f32 %0, %1, %2" : "=v"(r) : "v"(a), "v"(b));
    return r;
}

// raw v_exp_f32 (libm exp2f expands to ~6 instr of denorm handling)
__device__ __forceinline__ float fexp2(float x)
{
    float r;
    asm("v_exp_f32 %0, %1" : "=v"(r) : "v"(x));
    return r;
}

// LDS-only barrier: drains lgkmcnt but NOT vmcnt, so in-flight global->reg
// prefetch loads survive the barrier (hipcc's __syncthreads drains vmcnt(0),
// exposing the full load latency every tile -- verified: attn r7->r10 -5.6us).
__device__ __forceinline__ void barrier_lds()
{
    asm volatile("s_waitcnt lgkmcnt(0)" ::: "memory");
    __builtin_amdgcn_s_barrier();
    __builtin_amdgcn_sched_barrier(0);
}

// ---------------------------------------------------------------------------
// FUSED: six weight transposes (0..3071) + mask check (3072..4095) +
// q/k/v fp32->bf16 cast (4096..7167).  Unchanged (verified).
// ---------------------------------------------------------------------------
__global__ __launch_bounds__(256) void tw_mask(
    const float* __restrict__ WQ, const float* __restrict__ WK,
    const float* __restrict__ WV, const float* __restrict__ WO,
    const float* __restrict__ W1, const float* __restrict__ W2,
    bf16* __restrict__ WQt, bf16* __restrict__ WKt, bf16* __restrict__ WVt,
    bf16* __restrict__ WOt, bf16* __restrict__ W1t, bf16* __restrict__ W2t,
    const float* __restrict__ q, const float* __restrict__ k,
    const float* __restrict__ v,
    bf16* __restrict__ qb, bf16* __restrict__ kb, bf16* __restrict__ vb,
    const uint4* __restrict__ mask, int* __restrict__ flag)
{
    const int bid = blockIdx.x;
    if (bid >= 4096) {
        const int idx = bid - 4096;
        const float* src = idx < 1024 ? q : idx < 2048 ? k : v;
        bf16*       dst = idx < 1024 ? qb : idx < 2048 ? kb : vb;
        const size_t b4 = (size_t)(idx & 1023) * 1024;
#pragma unroll
        for (int i = 0; i < 4; ++i) {
            const float4 f = reinterpret_cast<const float4*>(src)[b4 + i * 256 + threadIdx.x];
            bf16x4 h;
            h[0] = (bf16)f.x; h[1] = (bf16)f.y; h[2] = (bf16)f.z; h[3] = (bf16)f.w;
            reinterpret_cast<bf16x4*>(dst)[b4 + i * 256 + threadIdx.x] = h;
        }
        return;
    }
    if (bid >= 3072) {
        const uint4* p = mask + (size_t)(bid - 3072) * 4096;
        unsigned nz = 0;
#pragma unroll
        for (int i = 0; i < 16; ++i) {
            const uint4 u = p[i * 256 + threadIdx.x];
            nz |= u.x | u.y | u.z | u.w;
        }
        if (nz) atomicOr(flag, 1);
        return;
    }
    __shared__ float tile[32][33];
    const float* in; bf16* out; int ip, op, cx, ry;
    if (bid < 1024) {
        const int w = bid >> 8, idx = bid & 255;
        in  = w == 0 ? WQ  : w == 1 ? WK  : w == 2 ? WV  : WO;
        out = w == 0 ? WQt : w == 1 ? WKt : w == 2 ? WVt : WOt;
        ip = 512; op = 512; cx = idx & 15; ry = idx >> 4;
    } else if (bid < 2048) {
        const int idx = bid - 1024;
        in = W1; out = W1t; ip = 2048; op = 512; cx = idx & 63; ry = idx >> 6;
    } else {
        const int idx = bid - 2048;
        in = W2; out = W2t; ip = 512; op = 2048; cx = idx & 15; ry = idx >> 4;
    }
    const int c0 = cx * 32, r0 = ry * 32;
    const int tx = threadIdx.x & 31, ty = threadIdx.x >> 5;
    for (int i = 0; i < 32; i += 8)
        tile[ty + i][tx] = in[(size_t)(r0 + ty + i) * ip + c0 + tx];
    __syncthreads();
    for (int i = 0; i < 32; i += 8)
        out[(size_t)(c0 + ty + i) * op + r0 + tx] = (bf16)tile[tx][ty + i];
}

// ---------------------------------------------------------------------------
// 128x128-tile GEMM (m97 structure) for W1 (N=2048). Unchanged (verified).
// ---------------------------------------------------------------------------
template <int ACT>
__global__ __launch_bounds__(256) void gemm128(const bf16* __restrict__ A,
                                               const bf16* __restrict__ Bt,
                                               bf16* __restrict__ C,
                                               int N, int K)
{
    __shared__ bf16 sA[128 * 64];
    __shared__ bf16 sB[128 * 64];

    const int t    = threadIdx.x;
    const int lane = t & 63;
    const int wave = t >> 6;
    const int wm   = wave >> 1;
    const int wn   = wave & 1;
    const int lr   = lane & 15;
    const int lq   = lane >> 4;

    const int m0 = blockIdx.y * 128;
    const int n0 = blockIdx.x * 128;

    const int srow = lane >> 3;
    const int scol = (lane & 7) * 8;

    f32x4 acc[4][4] = {};

    for (int k0 = 0; k0 < K; k0 += 64) {
        if (k0) __syncthreads();
#pragma unroll
        for (int i = 0; i < 4; ++i) {
            const int ch = wave * 4 + i;
            const int r  = ch * 8 + srow;
            gload16(A  + (size_t)(m0 + r) * K + k0 + scol, sA + ch * 512);
            gload16(Bt + (size_t)(n0 + r) * K + k0 + scol, sB + ch * 512);
        }
        __syncthreads();

#pragma unroll
        for (int kk = 0; kk < 2; ++kk) {
            bf16x8 af[4], bfr[4];
#pragma unroll
            for (int x = 0; x < 4; ++x) {
                af[x]  = *reinterpret_cast<const bf16x8*>(&sA[(wm * 64 + x * 16 + lr) * 64 + kk * 32 + lq * 8]);
                bfr[x] = *reinterpret_cast<const bf16x8*>(&sB[(wn * 64 + x * 16 + lr) * 64 + kk * 32 + lq * 8]);
            }
#pragma unroll
            for (int m = 0; m < 4; ++m)
#pragma unroll
                for (int n = 0; n < 4; ++n)
                    acc[m][n] = __builtin_amdgcn_mfma_f32_16x16x32_bf16(af[m], bfr[n], acc[m][n], 0, 0, 0);
        }
    }

#pragma unroll
    for (int n = 0; n < 4; ++n) {
        const int col = n0 + wn * 64 + n * 16 + lr;
#pragma unroll
        for (int m = 0; m < 4; ++m) {
            const int rowb = m0 + wm * 64 + m * 16 + lq * 4;
#pragma unroll
            for (int j = 0; j < 4; ++j) {
                float v = acc[m][n][j];
                if (ACT == 1) v = v > 0.f ? v : 0.f;
                C[(size_t)(rowb + j) * N + col] = (bf16)v;
            }
        }
    }
}

// ---------------------------------------------------------------------------
// QKV projection, pure-bf16 A, 64x128 tile; V written transposed to Vt.
// Q output pre-scaled by QSCL in fp32.  Unchanged (verified).
// ---------------------------------------------------------------------------
__global__ __launch_bounds__(256) void gemm64_qkvb(const bf16* __restrict__ qb,
                                                   const bf16* __restrict__ kb,
                                                   const bf16* __restrict__ vb,
                                                   const bf16* __restrict__ WQt,
                                                   const bf16* __restrict__ WKt,
                                                   const bf16* __restrict__ WVt,
                                                   bf16* __restrict__ Qb,
                                                   bf16* __restrict__ Kb,
                                                   bf16* __restrict__ Vt)
{
    __shared__ bf16 sA[64 * 64];
    __shared__ bf16 sB[128 * 64];

    const bf16* A  = blockIdx.z == 0 ? qb  : blockIdx.z == 1 ? kb  : vb;
    const bf16* Bt = blockIdx.z == 0 ? WQt : blockIdx.z == 1 ? WKt : WVt;
    const int K = DIN;

    const int t    = threadIdx.x;
    const int lane = t & 63;
    const int wave = t >> 6;
    const int lr   = lane & 15;
    const int lq   = lane >> 4;

    const int m0 = blockIdx.y * 64;
    const int n0 = blockIdx.x * 128;

    const int srow = lane >> 3;
    const int scol = (lane & 7) * 8;

    f32x4 acc[4][2] = {};

    for (int k0 = 0; k0 < K; k0 += 64) {
        if (k0) __syncthreads();
#pragma unroll
        for (int i = 0; i < 2; ++i) {
            const int ch = wave * 2 + i;
            gload16(A + (size_t)(m0 + ch * 8 + srow) * K + k0 + scol, sA + ch * 512);
        }
#pragma unroll
        for (int i = 0; i < 4; ++i) {
            const int ch = wave * 4 + i;
            gload16(Bt + (size_t)(n0 + ch * 8 + srow) * K + k0 + scol, sB + ch * 512);
        }
        __syncthreads();

#pragma unroll
        for (int kk = 0; kk < 2; ++kk) {
            bf16x8 af[4], bfr[2];
#pragma unroll
            for (int x = 0; x < 4; ++x)
                af[x] = *reinterpret_cast<const bf16x8*>(&sA[(x * 16 + lr) * 64 + kk * 32 + lq * 8]);
#pragma unroll
            for (int n = 0; n < 2; ++n)
                bfr[n] = *reinterpret_cast<const bf16x8*>(&sB[(wave * 32 + n * 16 + lr) * 64 + kk * 32 + lq * 8]);
#pragma unroll
            for (int m = 0; m < 4; ++m)
#pragma unroll
                for (int n = 0; n < 2; ++n)
                    acc[m][n] = __builtin_amdgcn_mfma_f32_16x16x32_bf16(af[m], bfr[n], acc[m][n], 0, 0, 0);
        }
    }

    if (blockIdx.z < 2) {
        bf16* C = blockIdx.z == 0 ? Qb : Kb;
        const float sc = blockIdx.z == 0 ? QSCL : 1.f;
#pragma unroll
        for (int n = 0; n < 2; ++n) {
            const int col = n0 + wave * 32 + n * 16 + lr;
#pragma unroll
            for (int m = 0; m < 4; ++m) {
                const int rowb = m0 + m * 16 + lq * 4;
#pragma unroll
                for (int j = 0; j < 4; ++j)
                    C[(size_t)(rowb + j) * DIN + col] = (bf16)(acc[m][n][j] * sc);
            }
        }
    } else {
        __syncthreads();
#pragma unroll
        for (int n = 0; n < 2; ++n)
#pragma unroll
            for (int m = 0; m < 4; ++m)
#pragma unroll
                for (int j = 0; j < 4; ++j)
                    sB[(wave * 32 + n * 16 + lr) * 64 + m * 16 + lq * 4 + j] = (bf16)acc[m][n][j];
        __syncthreads();
        const int c = t >> 1, half = t & 1;
#pragma unroll
        for (int qq = 0; qq < 4; ++qq) {
            const bf16x8 vv = *reinterpret_cast<const bf16x8*>(&sB[c * 64 + half * 32 + qq * 8]);
            *reinterpret_cast<bf16x8*>(Vt + (size_t)(n0 + c) * MROWS + m0 + half * 32 + qq * 8) = vv;
        }
    }
}

// ---------------------------------------------------------------------------
// Flash attention — UNCHANGED from round 11 (best measured; 2 blk/CU).
// ---------------------------------------------------------------------------
__global__ __launch_bounds__(256) void attn_kernel(const bf16* __restrict__ Qb,
                                                   const bf16* __restrict__ Kb,
                                                   const bf16* __restrict__ Vt,
                                                   const float* __restrict__ mask,
                                                   bf16* __restrict__ O,
                                                   const int* __restrict__ mzf)
{
    const int bi   = blockIdx.x;
    const int xcd  = bi & 7;
    const int slot = bi >> 3;
    const int pair = xcd * 4 + (slot >> 4);
    const int qt   = slot & 15;
    const int h    = pair >> 2;
    const int b    = pair & 3;

    const int t    = threadIdx.x;
    const int lane = t & 63;
    const int wave = t >> 6;
    const int l31  = lane & 31;
    const int hi   = lane >> 5;
    const int q0   = qt * 128;
    const bool useM = (*mzf != 0);

    __shared__ bf16 sK[64 * 64];
    __shared__ bf16 sV[64 * 64];
    __shared__ float sL[4][32];

    bf16x8 qf[4];
#pragma unroll
    for (int s = 0; s < 4; ++s)
        qf[s] = *reinterpret_cast<const bf16x8*>(
            Qb + (size_t)(b * SEQ + q0 + wave * 32 + l31) * DIN + h * 64 + s * 16 + hi * 8);

    f32x16 o0 = {}, o1 = {};
    float lacc = 0.f;

    const int sr  = t >> 2;
    const int c1  = t & 3;
    const int xsw = sr & 7;

    const bf16* kbase = Kb + (size_t)(b * SEQ) * DIN + h * 64;
    const bf16* vbase = Vt + (size_t)(h * 64 + sr) * MROWS + b * SEQ;

    constexpr float L2E = 1.4426950408889634f;

    int4 kr0 = *reinterpret_cast<const int4*>(kbase + (size_t)sr * DIN + c1 * 8);
    int4 kr1 = *reinterpret_cast<const int4*>(kbase + (size_t)sr * DIN + c1 * 8 + 32);
    int4 vr0 = *reinterpret_cast<const int4*>(vbase + c1 * 8);
    int4 vr1 = *reinterpret_cast<const int4*>(vbase + c1 * 8 + 32);

    for (int tile = 0; tile < SEQ / 64; ++tile) {
        if (tile) barrier_lds();

        *reinterpret_cast<int4*>(&sK[sr * 64 + ((c1    ) ^ xsw) * 8]) = kr0;
        *reinterpret_cast<int4*>(&sK[sr * 64 + ((c1 + 4) ^ xsw) * 8]) = kr1;
        *reinterpret_cast<int4*>(&sV[sr * 64 + ((c1    ) ^ xsw) * 8]) = vr0;
        *reinterpret_cast<int4*>(&sV[sr * 64 + ((c1 + 4) ^ xsw) * 8]) = vr1;

        if (tile + 1 < SEQ / 64) {
            const int k0 = (tile + 1) * 64;
            kr0 = *reinterpret_cast<const int4*>(kbase + (size_t)(k0 + sr) * DIN + c1 * 8);
            kr1 = *reinterpret_cast<const int4*>(kbase + (size_t)(k0 + sr) * DIN + c1 * 8 + 32);
            vr0 = *reinterpret_cast<const int4*>(vbase + k0 + c1 * 8);
            vr1 = *reinterpret_cast<const int4*>(vbase + k0 + c1 * 8 + 32);
        }
        barrier_lds();

        bf16x8 kf[2][4];
#pragma unroll
        for (int kb = 0; kb < 2; ++kb)
#pragma unroll
            for (int s = 0; s < 4; ++s) {
                const int r = kb * 32 + l31;
                kf[kb][s] = *reinterpret_cast<const bf16x8*>(
                    &sK[r * 64 + ((hi + 2 * s) ^ (r & 7)) * 8]);
            }
        bf16x8 vf[2][4];
#pragma unroll
        for (int dt = 0; dt < 2; ++dt)
#pragma unroll
            for (int c = 0; c < 4; ++c) {
                const int r = dt * 32 + l31;
                vf[dt][c] = *reinterpret_cast<const bf16x8*>(
                    &sV[r * 64 + ((hi + 2 * c) ^ (r & 7)) * 8]);
            }

        f32x16 st0 = {}, st1 = {};
#pragma unroll
        for (int s = 0; s < 4; ++s) {
            st0 = __builtin_amdgcn_mfma_f32_32x32x16_bf16(kf[0][s], qf[s], st0, 0, 0, 0);
            st1 = __builtin_amdgcn_mfma_f32_32x32x16_bf16(kf[1][s], qf[s], st1, 0, 0, 0);
        }

        float p[32];
        if (useM) {
            const float* mrow = mask + ((size_t)(b * SEQ + q0 + wave * 32 + l31)) * SEQ + tile * 64;
#pragma unroll
            for (int r = 0; r < 16; ++r) {
                const int kk = (r & 3) + 8 * (r >> 2) + 4 * hi;
                p[r]      = fexp2(st0[r] + mrow[kk]      * L2E);
                p[16 + r] = fexp2(st1[r] + mrow[32 + kk] * L2E);
            }
        } else {
#pragma unroll
            for (int r = 0; r < 16; ++r) {
                p[r]      = fexp2(st0[r]);
                p[16 + r] = fexp2(st1[r]);
            }
        }
        {
            float s0 = 0.f, s1 = 0.f, s2 = 0.f, s3 = 0.f;
#pragma unroll
            for (int r = 0; r < 8; ++r) {
                s0 += p[r];
                s1 += p[8 + r];
                s2 += p[16 + r];
                s3 += p[24 + r];
            }
            lacc += (s0 + s1) + (s2 + s3);
        }

        bf16x8 pa[4];
#pragma unroll
        for (int c = 0; c < 4; ++c) {
            const int bse = c * 8;
            unsigned u0 = cvtpk(p[bse + 0], p[bse + 1]);
            unsigned u1 = cvtpk(p[bse + 2], p[bse + 3]);
            unsigned u2 = cvtpk(p[bse + 4], p[bse + 5]);
            unsigned u3 = cvtpk(p[bse + 6], p[bse + 7]);
            const uint2v r02 = __builtin_amdgcn_permlane32_swap(u0, u2, false, false);
            const uint2v r13 = __builtin_amdgcn_permlane32_swap(u1, u3, false, false);
            union { unsigned u[4]; bf16x8 v; } pk;
            pk.u[0] = r02.x; pk.u[1] = r13.x; pk.u[2] = r02.y; pk.u[3] = r13.y;
            pa[c] = pk.v;
        }

#pragma unroll
        for (int c = 0; c < 4; ++c) {
            o0 = __builtin_amdgcn_mfma_f32_32x32x16_bf16(pa[c], vf[0][c], o0, 0, 0, 0);
            o1 = __builtin_amdgcn_mfma_f32_32x32x16_bf16(pa[c], vf[1][c], o1, 0, 0, 0);
        }
    }

    lacc += __shfl_xor(lacc, 32);
    if (hi == 0) sL[wave][l31] = lacc;

#pragma unroll
    for (int r = 0; r < 16; ++r) {
        const int qr = (r & 3) + 8 * (r >> 2) + 4 * hi;
        const float inv = 1.f / sL[wave][qr];
        const size_t rowoff = (size_t)(b * SEQ + q0 + wave * 32 + qr) * DIN + h * 64;
        O[rowoff + l31]      = (bf16)(o0[r] * inv);
        O[rowoff + 32 + l31] = (bf16)(o1[r] * inv);
    }
}

// ---------------------------------------------------------------------------
// FUSED GEMM + residual + LayerNorm (WO and W2 paths).  ROUND-13: same
// schedule as r12 (reg-staged dbuf, XOR-swizzled LDS, one lgkm-only barrier
// per step -- swizzle VERIFIED: conflicts 9.5e6 -> 67K in r12) but staging
// registers are MACRO-EXPANDED NAMED int4 variables.  r12's lambda pointer
// params sent the arrays to scratch (rule #20: WRITE_SIZE 540 MB, VGPR 88).
// Note: for all staged rows, row&7 == srow, so write chunk = scol8 ^ srow.
// ---------------------------------------------------------------------------
__global__ __launch_bounds__(512) void gemm_ln(const bf16* __restrict__ A,
                                               const bf16* __restrict__ Bt,
                                               const float* __restrict__ X,
                                               bf16* __restrict__ Onb,
                                               float* __restrict__ Onf,
                                               int K)
{
    __shared__ bf16 sA[2][32 * 64];
    __shared__ bf16 sB[2][512 * 64];
    __shared__ float sRed[32][8];
    __shared__ float sMu[32];
    __shared__ float sRstd[32];

    const int t     = threadIdx.x;
    const int lane  = t & 63;
    const int w     = t >> 6;
    const int lr    = lane & 15;
    const int lq    = lane >> 4;
    const int srow  = lane >> 3;        // 0..7
    const int scol8 = lane & 7;         // 16B-chunk index within a 64-elem row

    const int m0 = blockIdx.x * 32;

    // named staging registers (rule #20: no arrays through pointers)
    int4 b0, b1, b2, b3, b4, b5, b6, b7, bA;
    int4 c0, c1, c2, c3, c4, c5, c6, c7, cA;
    bA = make_int4(0, 0, 0, 0);
    cA = make_int4(0, 0, 0, 0);

#define GLN_LOAD(R0, R1, R2, R3, R4, R5, R6, R7, RA, S)                          \
    {                                                                            \
        const bf16* bp_ = Bt + (size_t)(w * 64 + srow) * K + (S) * 64 + scol8 * 8; \
        R0 = *reinterpret_cast<const int4*>(bp_ + (size_t) 0 * K);               \
        R1 = *reinterpret_cast<const int4*>(bp_ + (size_t) 8 * K);               \
        R2 = *reinterpret_cast<const int4*>(bp_ + (size_t)16 * K);               \
        R3 = *reinterpret_cast<const int4*>(bp_ + (size_t)24 * K);               \
        R4 = *reinterpret_cast<const int4*>(bp_ + (size_t)32 * K);               \
        R5 = *reinterpret_cast<const int4*>(bp_ + (size_t)40 * K);               \
        R6 = *reinterpret_cast<const int4*>(bp_ + (size_t)48 * K);               \
        R7 = *reinterpret_cast<const int4*>(bp_ + (size_t)56 * K);               \
        if (w < 4)                                                               \
            RA = *reinterpret_cast<const int4*>(A + (size_t)(m0 + w * 8 + srow) * K + (S) * 64 + scol8 * 8); \
    }

#define GLN_WRITE(R0, R1, R2, R3, R4, R5, R6, R7, RA, BB)                        \
    {                                                                            \
        bf16* wp_ = &sB[BB][(w * 64 + srow) * 64 + (scol8 ^ srow) * 8];          \
        *reinterpret_cast<int4*>(wp_ + 0 * 512) = R0;                            \
        *reinterpret_cast<int4*>(wp_ + 1 * 512) = R1;                            \
        *reinterpret_cast<int4*>(wp_ + 2 * 512) = R2;                            \
        *reinterpret_cast<int4*>(wp_ + 3 * 512) = R3;                            \
        *reinterpret_cast<int4*>(wp_ + 4 * 512) = R4;                            \
        *reinterpret_cast<int4*>(wp_ + 5 * 512) = R5;                            \
        *reinterpret_cast<int4*>(wp_ + 6 * 512) = R6;                            \
        *reinterpret_cast<int4*>(wp_ + 7 * 512) = R7;                            \
        if (w < 4)                                                               \
            *reinterpret_cast<int4*>(&sA[BB][(w * 8 + srow) * 64 + (scol8 ^ srow) * 8]) = RA; \
    }

    f32x4 acc[2][4] = {};
    const int steps = K / 64;

    auto compute = [&](int bb) {
#pragma unroll
        for (int kk = 0; kk < 2; ++kk) {
            bf16x8 af[2], bfr[4];
#pragma unroll
            for (int m = 0; m < 2; ++m) {
                const int row = m * 16 + lr;
                af[m] = *reinterpret_cast<const bf16x8*>(
                    &sA[bb][row * 64 + (((kk * 4 + lq) ^ (row & 7)) * 8)]);
            }
#pragma unroll
            for (int n = 0; n < 4; ++n) {
                const int row = w * 64 + n * 16 + lr;
                bfr[n] = *reinterpret_cast<const bf16x8*>(
                    &sB[bb][row * 64 + (((kk * 4 + lq) ^ (row & 7)) * 8)]);
            }
#pragma unroll
            for (int m = 0; m < 2; ++m)
#pragma unroll
                for (int n = 0; n < 4; ++n)
                    acc[m][n] = __builtin_amdgcn_mfma_f32_16x16x32_bf16(af[m], bfr[n], acc[m][n], 0, 0, 0);
        }
    };

    // prologue: tile0 -> regs -> buf0; issue tile1 loads; one barrier
    GLN_LOAD(b0, b1, b2, b3, b4, b5, b6, b7, bA, 0);
    GLN_WRITE(b0, b1, b2, b3, b4, b5, b6, b7, bA, 0);
    if (steps > 1) GLN_LOAD(c0, c1, c2, c3, c4, c5, c6, c7, cA, 1);
    barrier_lds();

    for (int s = 0; s < steps; s += 2) {
        // even: compute buf0; write tile s+1 (c regs) -> buf1; load s+2 -> b
        compute(0);
        if (s + 1 < steps) GLN_WRITE(c0, c1, c2, c3, c4, c5, c6, c7, cA, 1);
        if (s + 2 < steps) GLN_LOAD(b0, b1, b2, b3, b4, b5, b6, b7, bA, s + 2);
        barrier_lds();
        if (s + 1 >= steps) break;
        // odd: compute buf1; write tile s+2 (b regs) -> buf0; load s+3 -> c
        compute(1);
        if (s + 2 < steps) GLN_WRITE(b0, b1, b2, b3, b4, b5, b6, b7, bA, 0);
        if (s + 3 < steps) GLN_LOAD(c0, c1, c2, c3, c4, c5, c6, c7, cA, s + 3);
        barrier_lds();
    }
#undef GLN_LOAD
#undef GLN_WRITE

    // residual add (fp32), in place
#pragma unroll
    for (int m = 0; m < 2; ++m)
#pragma unroll
        for (int n = 0; n < 4; ++n)
#pragma unroll
            for (int j = 0; j < 4; ++j)
                acc[m][n][j] += X[(size_t)(m0 + m * 16 + lq * 4 + j) * DIN + w * 64 + n * 16 + lr];

#pragma unroll
    for (int m = 0; m < 2; ++m)
#pragma unroll
        for (int j = 0; j < 4; ++j) {
            float s = acc[m][0][j] + acc[m][1][j] + acc[m][2][j] + acc[m][3][j];
            s += __shfl_xor(s, 1); s += __shfl_xor(s, 2);
            s += __shfl_xor(s, 4); s += __shfl_xor(s, 8);
            if (lr == 0) sRed[m * 16 + lq * 4 + j][w] = s;
        }
    __syncthreads();
    if (t < 32) {
        float s = 0.f;
#pragma unroll
        for (int ww = 0; ww < 8; ++ww) s += sRed[t][ww];
        sMu[t] = s * (1.f / DIN);
    }
    __syncthreads();

#pragma unroll
    for (int m = 0; m < 2; ++m)
#pragma unroll
        for (int j = 0; j < 4; ++j) {
            const float mu = sMu[m * 16 + lq * 4 + j];
            float s = 0.f;
#pragma unroll
            for (int n = 0; n < 4; ++n) {
                const float d = acc[m][n][j] - mu;
                s += d * d;
            }
            s += __shfl_xor(s, 1); s += __shfl_xor(s, 2);
            s += __shfl_xor(s, 4); s += __shfl_xor(s, 8);
            if (lr == 0) sRed[m * 16 + lq * 4 + j][w] = s;
        }
    __syncthreads();
    if (t < 32) {
        float s = 0.f;
#pragma unroll
        for (int ww = 0; ww < 8; ++ww) s += sRed[t][ww];
        sRstd[t] = rsqrtf(s * (1.f / DIN) + 1e-5f);
    }
    __syncthreads();

#pragma unroll
    for (int m = 0; m < 2; ++m)
#pragma unroll
        for (int j = 0; j < 4; ++j) {
            const int rl = m * 16 + lq * 4 + j;
            const float mu = sMu[rl], rstd = sRstd[rl];
            const size_t rowoff = (size_t)(m0 + rl) * DIN;
#pragma unroll
            for (int n = 0; n < 4; ++n) {
                const float r = (acc[m][n][j] - mu) * rstd;
                const int col = w * 64 + n * 16 + lr;
                if (Onb) Onb[rowoff + col] = (bf16)r;
                if (Onf) Onf[rowoff + col] = r;
            }
        }
}

// ---------------------------------------------------------------------------
extern "C" void kernel_launch(void* const* d_in, const int* in_sizes, int n_in,
                              void* d_out, int out_size, void* d_ws, size_t ws_size,
                              hipStream_t stream)
{
    const float* query = (const float*)d_in[0];
    const float* key   = (const float*)d_in[1];
    const float* value = (const float*)d_in[2];
    const float* mask  = (const float*)d_in[3];
    const float* WQ    = (const float*)d_in[4];
    const float* WK    = (const float*)d_in[5];
    const float* WV    = (const float*)d_in[6];
    const float* WO    = (const float*)d_in[7];
    const float* W1    = (const float*)d_in[8];
    const float* W2    = (const float*)d_in[9];

    char* w = (char*)d_ws;
    size_t off = 0;
    auto carve2 = [&](size_t elems) { bf16* p = (bf16*)(w + off); off += elems * 2; return p; };
    auto carve4 = [&](size_t elems) { float* p = (float*)(w + off); off += elems * 4; return p; };

    bf16* Qb    = carve2((size_t)MROWS * DIN);
    bf16* Kb    = carve2((size_t)MROWS * DIN);
    bf16* Vb    = carve2((size_t)MROWS * DIN);   // attn output (Ob)
    bf16* Vt    = carve2((size_t)MROWS * DIN);
    bf16* Mid   = carve2((size_t)MROWS * DMID);
    float* Ln1f = carve4((size_t)MROWS * DIN);
    bf16* WQt   = carve2((size_t)DIN * DIN);
    bf16* WKt   = carve2((size_t)DIN * DIN);
    bf16* WVt   = carve2((size_t)DIN * DIN);
    bf16* WOt   = carve2((size_t)DIN * DIN);
    bf16* W1t   = carve2((size_t)DIN * DMID);
    bf16* W2t   = carve2((size_t)DMID * DIN);
    int*  mzf   = (int*)(w + off); off += 16;
    if (off > ws_size) return;

    bf16* Ob   = Vb;
    bf16* Ln1b = Kb;
    bf16* qb = Mid;
    bf16* kb = Mid + (size_t)MROWS * DIN;
    bf16* vb = Mid + (size_t)2 * MROWS * DIN;

    const dim3 blk(256);

    hipMemsetAsync(mzf, 0, 4, stream);

    tw_mask<<<dim3(7168), blk, 0, stream>>>(WQ, WK, WV, WO, W1, W2,
                                            WQt, WKt, WVt, WOt, W1t, W2t,
                                            query, key, value, qb, kb, vb,
                                            (const uint4*)mask, mzf);

    gemm64_qkvb<<<dim3(DIN / 128, MROWS / 64, 3), blk, 0, stream>>>(qb, kb, vb,
                                                                    WQt, WKt, WVt, Qb, Kb, Vt);

    // attention: unchanged (2 blocks/CU)
    attn_kernel<<<dim3(512), blk, 0, stream>>>(Qb, Kb, Vt, mask, Ob, mzf);

    gemm_ln<<<dim3(MROWS / 32), dim3(512), 0, stream>>>(Ob, WOt, query, Ln1b, Ln1f, DIN);

    gemm128<1><<<dim3(DMID / 128, MROWS / 128), blk, 0, stream>>>(Ln1b, W1t, Mid, DMID, DIN);

    gemm_ln<<<dim3(MROWS / 32), dim3(512), 0, stream>>>(Mid, W2t, Ln1f,
                                                        (bf16*)nullptr, (float*)d_out, DMID);
}